// Round 1
// baseline (394.342 us; speedup 1.0000x reference)
//
#include <hip/hip_runtime.h>

static constexpr int HID  = 32;
static constexpr int LEN  = 32768;
static constexpr int HOP  = 256;
static constexpr int NKL  = 128;   // LEN / HOP
static constexpr int NOUT = 64;
#define SLOPE 0.2f

__device__ __forceinline__ float leaky(float x) { return x >= 0.0f ? x : SLOPE * x; }

// One block per (b, kl) chunk. 256 threads.
// LDS: xs[32][264] = leaky(hidden) with halo (positions t0-4 .. t0+259),
//      later reused as conv-output ys[o][sc] (sc 0..257 -> pos t0-1+sc).
// wbuf: union of transposed conv weights (3*32*32) then LVC weights (3*32*64).
__global__ __launch_bounds__(256, 2) void univnet_lvc_fused(
    const float* __restrict__ h,     // [16][32][32768]
    const float* __restrict__ kern,  // [16][32][64][3][128]
    const float* __restrict__ bias,  // [16][64][128]
    const float* __restrict__ cw,    // [32][32][3]  (O,I,K)
    const float* __restrict__ cb,    // [32]
    float* __restrict__ out)         // [16][32][32768]
{
    const int blk = blockIdx.x;          // 0..2047
    const int b   = blk >> 7;
    const int kl  = blk & (NKL - 1);
    const int t0  = kl * HOP;
    const int tid = threadIdx.x;

    __shared__ float xs[32 * 264];
    __shared__ float wbuf[3 * 32 * 64];  // 6144 floats

    // ---- Phase 0a: conv weights transposed: wbuf[(k*32+i)*32+o] = cw[o][i][k]
    for (int idx = tid; idx < 3 * 32 * 32; idx += 256) {
        int o = idx & 31;
        int r = idx >> 5;        // k*32 + i
        int i = r & 31;
        int k = r >> 5;
        wbuf[idx] = cw[(o * 32 + i) * 3 + k];
    }
    // ---- Phase 0b: xs[i][si] = leaky(h[b][i][t0-4+si]), 0 outside signal
    const float* hb = h + (size_t)b * (HID * LEN);
    for (int idx = tid; idx < 32 * 264; idx += 256) {
        int i  = idx / 264;
        int si = idx - i * 264;
        int pos = t0 - 4 + si;
        float v = 0.0f;
        if (pos >= 0 && pos < LEN) v = leaky(hb[i * LEN + pos]);
        xs[idx] = v;
    }
    __syncthreads();

    const int og = tid >> 5;   // 0..7
    const int s0 = tid & 31;

    // ---- Phase 1: dilated conv (dil=3, pad=3). Output sc in 0..257 maps to
    // position t0-1+sc; input index into xs is sc + 3k.
    const int o0c = og * 4;                 // conv channel tile base (0..28)
    float ya[4][8];
    {
        float acc[4][8];
        #pragma unroll
        for (int oo = 0; oo < 4; oo++) {
            float bb = cb[o0c + oo];
            #pragma unroll
            for (int j = 0; j < 8; j++) acc[oo][j] = bb;
        }
        for (int i = 0; i < 32; i++) {
            const float* xrow = xs + i * 264;
            float w[3][4];
            #pragma unroll
            for (int k = 0; k < 3; k++) {
                const float* wp = wbuf + (k * 32 + i) * 32 + o0c;
                w[k][0] = wp[0]; w[k][1] = wp[1]; w[k][2] = wp[2]; w[k][3] = wp[3];
            }
            #pragma unroll
            for (int j = 0; j < 8; j++) {
                int sc = s0 + 32 * j;
                float x0 = xrow[sc];
                float x1 = xrow[sc + 3];
                float x2 = xrow[sc + 6];
                #pragma unroll
                for (int oo = 0; oo < 4; oo++)
                    acc[oo][j] += w[0][oo] * x0 + w[1][oo] * x1 + w[2][oo] * x2;
            }
        }
        #pragma unroll
        for (int oo = 0; oo < 4; oo++)
            #pragma unroll
            for (int j = 0; j < 8; j++) ya[oo][j] = leaky(acc[oo][j]);
    }
    // halo columns sc = 256, 257 (one output each for threads 0..63)
    float yhalo = 0.0f;
    int halo_o = 0, halo_sc = 0;
    if (tid < 64) {
        halo_o  = tid >> 1;
        halo_sc = 256 + (tid & 1);
        float acc = cb[halo_o];
        for (int i = 0; i < 32; i++) {
            const float* xrow = xs + i * 264;
            #pragma unroll
            for (int k = 0; k < 3; k++)
                acc += wbuf[(k * 32 + i) * 32 + halo_o] * xrow[halo_sc + 3 * k];
        }
        yhalo = leaky(acc);
    }
    __syncthreads();   // everyone done READING xs (and cwt in wbuf)

    // ---- Phase 1.5: write conv output into xs (reuse). Zero the columns that
    // correspond to positions outside [0, LEN): the reference zero-pads the
    // conv OUTPUT for the LVC window.
    #pragma unroll
    for (int oo = 0; oo < 4; oo++)
        #pragma unroll
        for (int j = 0; j < 8; j++) {
            int sc  = s0 + 32 * j;
            int pos = t0 - 1 + sc;
            xs[(o0c + oo) * 264 + sc] = (pos >= 0 && pos < LEN) ? ya[oo][j] : 0.0f;
        }
    if (tid < 64) {
        int pos = t0 - 1 + halo_sc;
        xs[halo_o * 264 + halo_sc] = (pos >= 0 && pos < LEN) ? yhalo : 0.0f;
    }
    // load LVC weights for this (b,kl): wbuf[(k*32+i)*64+o] = kern[b][i][o][k][kl]
    const float* kb = kern + (size_t)b * (32 * 64 * 3 * 128);
    for (int idx = tid; idx < 3 * 32 * 64; idx += 256) {
        int o = idx & 63;
        int r = idx >> 6;      // k*32 + i
        int i = r & 31;
        int k = r >> 5;
        wbuf[idx] = kb[((i * 64 + o) * 3 + k) * 128 + kl];
    }
    __syncthreads();

    // ---- Phase 2: LVC conv (K=3, pad=1) + bias. Thread owns gate pair:
    // channels o0l..o0l+3 (sigmoid half) and o0l+32..+35 (tanh half).
    const int o0l = og * 4;
    float accA[4][8], accB[4][8];
    const float* bb = bias + (size_t)b * 64 * 128 + kl;
    #pragma unroll
    for (int oo = 0; oo < 4; oo++) {
        float bA = bb[(o0l + oo) * 128];
        float bB = bb[(o0l + 32 + oo) * 128];
        #pragma unroll
        for (int j = 0; j < 8; j++) { accA[oo][j] = bA; accB[oo][j] = bB; }
    }
    for (int i = 0; i < 32; i++) {
        const float* yrow = xs + i * 264;
        float wA[3][4], wB[3][4];
        #pragma unroll
        for (int k = 0; k < 3; k++) {
            const float* wp = wbuf + (k * 32 + i) * 64 + o0l;
            wA[k][0] = wp[0];  wA[k][1] = wp[1];  wA[k][2] = wp[2];  wA[k][3] = wp[3];
            wB[k][0] = wp[32]; wB[k][1] = wp[33]; wB[k][2] = wp[34]; wB[k][3] = wp[35];
        }
        #pragma unroll
        for (int j = 0; j < 8; j++) {
            int s = s0 + 32 * j;
            float x0 = yrow[s];       // window offsets k-1 -> ys index s+k
            float x1 = yrow[s + 1];
            float x2 = yrow[s + 2];
            #pragma unroll
            for (int oo = 0; oo < 4; oo++) {
                accA[oo][j] += wA[0][oo] * x0 + wA[1][oo] * x1 + wA[2][oo] * x2;
                accB[oo][j] += wB[0][oo] * x0 + wB[1][oo] * x1 + wB[2][oo] * x2;
            }
        }
    }

    // ---- Epilogue: residual + sigmoid(A)*tanh(B)
    float* ob = out + (size_t)b * (HID * LEN);
    #pragma unroll
    for (int oo = 0; oo < 4; oo++) {
        int o = o0l + oo;
        #pragma unroll
        for (int j = 0; j < 8; j++) {
            int s = s0 + 32 * j;
            float a = accA[oo][j];
            float c = accB[oo][j];
            c = fminf(fmaxf(c, -20.0f), 20.0f);
            float sg = 1.0f / (1.0f + __expf(-a));
            float e2 = __expf(-2.0f * c);
            float th = (1.0f - e2) / (1.0f + e2);
            size_t off = (size_t)o * LEN + t0 + s;
            ob[off] = hb[off] + sg * th;
        }
    }
}

extern "C" void kernel_launch(void* const* d_in, const int* in_sizes, int n_in,
                              void* d_out, int out_size, void* d_ws, size_t ws_size,
                              hipStream_t stream) {
    const float* h    = (const float*)d_in[0];
    const float* kern = (const float*)d_in[1];
    const float* bias = (const float*)d_in[2];
    const float* cw   = (const float*)d_in[3];
    const float* cb   = (const float*)d_in[4];
    float* outp = (float*)d_out;

    dim3 grid(16 * NKL);   // one block per (b, kl)
    dim3 block(256);
    univnet_lvc_fused<<<grid, block, 0, stream>>>(h, kern, bias, cw, cb, outp);
}

// Round 3
// 337.072 us; speedup vs baseline: 1.1699x; 1.1699x over previous
//
#include <hip/hip_runtime.h>

static constexpr int HID  = 32;
static constexpr int LEN  = 32768;
static constexpr int NKL  = 128;   // LEN / HOP(256)
static constexpr int HALF = 128;   // positions per block
static constexpr int XCOLS = 136;  // HALF + 8 halo columns
#define SLOPE 0.2f

__device__ __forceinline__ float leaky(float x) { return x >= 0.0f ? x : SLOPE * x; }

// ---------------------------------------------------------------------------
// Repack kern[b][i][o][k][kl] (stride-128 in kl) -> rp[b][kl][(k*32+i)*64+o]
// so the fused kernel reads its 24 KB of per-(b,kl) weights fully coalesced.
// Block = (b, i, kl-tile of 32). LDS tile 192 rows (o*3+k) x 32 kl, pad 33.
// ---------------------------------------------------------------------------
__global__ __launch_bounds__(256) void repack_kernel(
    const float* __restrict__ kern, float* __restrict__ rp)
{
    const int blk = blockIdx.x;        // 16 * 32 * 4 = 2048
    const int b   = blk >> 7;
    const int rem = blk & 127;
    const int i   = rem >> 2;
    const int kl0 = (rem & 3) << 5;
    const int tid = threadIdx.x;

    __shared__ float t[192 * 33];

    const int klx = tid & 31;
    for (int lr = tid >> 5; lr < 192; lr += 8)   // lr = o*3+k, coalesced reads
        t[lr * 33 + klx] =
            kern[((size_t)(b * 6144 + i * 192 + lr)) * 128 + kl0 + klx];
    __syncthreads();

    const int o = tid & 63;
    for (int seg = tid >> 6; seg < 96; seg += 4) {   // seg = klw*3 + k
        int klw = seg / 3;
        int k   = seg - 3 * klw;
        rp[((size_t)(b * NKL + kl0 + klw)) * 6144 + (k * 32 + i) * 64 + o] =
            t[(o * 3 + k) * 33 + klw];               // 2-way bank alias: free
    }
}

// ---------------------------------------------------------------------------
// Fused conv + LVC + gate + residual. One block per (b, half-chunk of 128).
// Thread (og = tid>>5, s0 = tid&31) owns 4 channels x 4 consecutive positions
// -> every LDS/global access is a contiguous 16B (or 8B) vector op.
// ---------------------------------------------------------------------------
__global__ __launch_bounds__(256, 3) void univnet_fused(
    const float* __restrict__ h,     // [16][32][32768]
    const float* __restrict__ kern,  // original layout (fallback gather)
    const float* __restrict__ bias,  // [16][64][128]
    const float* __restrict__ cw,    // [32][32][3]
    const float* __restrict__ cb,    // [32]
    const float* __restrict__ krp,   // repacked weights (or unused)
    float* __restrict__ out,
    int use_rp)
{
    const int blk = blockIdx.x;      // 0..4095
    const int b   = blk >> 8;
    const int hc  = blk & 255;
    const int p0  = hc << 7;         // chunk start position
    const int kl  = hc >> 1;
    const int tid = threadIdx.x;
    const int og  = tid >> 5;
    const int s0  = tid & 31;
    const int o0  = og << 2;         // 4-channel tile base

    __shared__ float xs[HID * XCOLS];     // 17408 B: leaky(x) w/ halo, later ys
    __shared__ float wbuf[3 * HID * 64];  // 24576 B: conv wt (first half), then LVC wt

    const float* hb = h + (size_t)b * (HID * LEN);

    // ---- prefetch LVC weights into registers (hidden behind conv phase) ----
    float4 wv[6];
    if (use_rp) {
        const float4* rp4 = (const float4*)(krp + ((size_t)(b * NKL + kl)) * 6144);
        #pragma unroll
        for (int p = 0; p < 6; p++) wv[p] = rp4[p * 256 + tid];
    }
    // ---- prefetch bias (broadcast within og-group, L2-hot) ----
    const float* bb = bias + (size_t)b * 64 * NKL + kl;
    float bA[4], bB[4];
    #pragma unroll
    for (int oo = 0; oo < 4; oo++) {
        bA[oo] = bb[(o0 + oo) * NKL];
        bB[oo] = bb[(o0 + 32 + oo) * NKL];
    }

    // ---- stage conv weights transposed: wbuf[(k*32+i)*32+o] ----
    for (int idx = tid; idx < 3 * 32 * 32; idx += 256) {
        int o = idx & 31;
        int r = idx >> 5;
        int i = r & 31;
        int k = r >> 5;
        wbuf[idx] = cw[(o * 32 + i) * 3 + k];
    }

    // ---- stage xs[i][c] = leaky(h[b][i][p0-4+c]), c = 0..135 ----
    const bool edge = (p0 == 0) || (p0 == LEN - HALF);
    if (!edge) {
        for (int idx = tid; idx < HID * 34; idx += 256) {
            int i  = idx / 34;
            int c4 = idx - i * 34;
            float4 v = *(const float4*)(hb + (size_t)i * LEN + p0 - 4 + 4 * c4);
            float4 w;
            w.x = leaky(v.x); w.y = leaky(v.y); w.z = leaky(v.z); w.w = leaky(v.w);
            *(float4*)(xs + i * XCOLS + 4 * c4) = w;
        }
    } else {
        for (int idx = tid; idx < HID * XCOLS; idx += 256) {
            int i = idx / XCOLS;
            int c = idx - i * XCOLS;
            int pos = p0 - 4 + c;
            float v = 0.0f;
            if (pos >= 0 && pos < LEN) v = leaky(hb[(size_t)i * LEN + pos]);
            xs[i * XCOLS + c] = v;
        }
    }
    __syncthreads();

    // ---- Phase 1: dilated conv (dil=3). Output col c uses xs[c+{0,3,6}],
    //      col c <-> position p0-1+c. Thread: cols 4*s0..4*s0+3 (+halo 128/129).
    float cacc[4][4];   // [oo][jj]
    float hacc[4];
    #pragma unroll
    for (int oo = 0; oo < 4; oo++) {
        float bv = cb[o0 + oo];
        #pragma unroll
        for (int jj = 0; jj < 4; jj++) cacc[oo][jj] = bv;
        hacc[oo] = bv;
    }
    for (int i = 0; i < HID; i++) {
        const float* xrow = xs + i * XCOLS;
        float4 w4[3];
        #pragma unroll
        for (int k = 0; k < 3; k++)
            w4[k] = *(const float4*)(wbuf + (k * 32 + i) * 32 + o0);
        float x[10];
        float4 t0v = *(const float4*)(xrow + 4 * s0);
        float4 t1v = *(const float4*)(xrow + 4 * s0 + 4);
        float2 t2v = *(const float2*)(xrow + 4 * s0 + 8);
        x[0] = t0v.x; x[1] = t0v.y; x[2] = t0v.z; x[3] = t0v.w;
        x[4] = t1v.x; x[5] = t1v.y; x[6] = t1v.z; x[7] = t1v.w;
        x[8] = t2v.x; x[9] = t2v.y;
        #pragma unroll
        for (int jj = 0; jj < 4; jj++) {
            #pragma unroll
            for (int k = 0; k < 3; k++) {
                float xv = x[jj + 3 * k];
                const float* wk = (const float*)&w4[k];
                #pragma unroll
                for (int oo = 0; oo < 4; oo++)
                    cacc[oo][jj] += wk[oo] * xv;
            }
        }
        if (s0 < 2) {  // halo cols 128, 129
            int c = HALF + s0;
            #pragma unroll
            for (int k = 0; k < 3; k++) {
                float xv = xrow[c + 3 * k];
                const float* wk = (const float*)&w4[k];
                #pragma unroll
                for (int oo = 0; oo < 4; oo++)
                    hacc[oo] += wk[oo] * xv;
            }
        }
    }
    __syncthreads();   // all xs / conv-weight reads complete

    // ---- Phase 1.5: ys[o][c] = leaky(conv) (zero outside signal) into xs ----
    #pragma unroll
    for (int oo = 0; oo < 4; oo++) {
        float4 v;
        float* vp = (float*)&v;
        #pragma unroll
        for (int jj = 0; jj < 4; jj++) {
            int c   = 4 * s0 + jj;
            int pos = p0 - 1 + c;
            float y = leaky(cacc[oo][jj]);
            vp[jj] = (pos >= 0 && pos < LEN) ? y : 0.0f;
        }
        *(float4*)(xs + (o0 + oo) * XCOLS + 4 * s0) = v;
    }
    if (s0 < 2) {
        int c   = HALF + s0;
        int pos = p0 - 1 + c;
        #pragma unroll
        for (int oo = 0; oo < 4; oo++) {
            float y = leaky(hacc[oo]);
            xs[(o0 + oo) * XCOLS + c] = (pos < LEN) ? y : 0.0f;
        }
    }
    // ---- drop prefetched LVC weights into wbuf[(k*32+i)*64+o] ----
    if (use_rp) {
        float4* w4p = (float4*)wbuf;
        #pragma unroll
        for (int p = 0; p < 6; p++) w4p[p * 256 + tid] = wv[p];
    } else {
        const float* kb = kern + (size_t)b * (32 * 64 * 3 * 128);
        for (int idx = tid; idx < 3 * 32 * 64; idx += 256) {
            int o = idx & 63;
            int r = idx >> 6;
            int i = r & 31;
            int k = r >> 5;
            wbuf[idx] = kb[((i * 64 + o) * 3 + k) * 128 + kl];
        }
    }
    __syncthreads();

    // ---- Phase 2: LVC. Out position p = p0 + 4*s0 + jj uses ys cols s..s+2 ----
    float accA[4][4], accB[4][4];
    #pragma unroll
    for (int oo = 0; oo < 4; oo++)
        #pragma unroll
        for (int jj = 0; jj < 4; jj++) { accA[oo][jj] = bA[oo]; accB[oo][jj] = bB[oo]; }

    for (int i = 0; i < HID; i++) {
        const float* yrow = xs + i * XCOLS;
        float4 wA[3], wB[3];
        #pragma unroll
        for (int k = 0; k < 3; k++) {
            const float* wp = wbuf + (k * 32 + i) * 64 + o0;
            wA[k] = *(const float4*)wp;
            wB[k] = *(const float4*)(wp + 32);
        }
        float y[6];
        float4 u0 = *(const float4*)(yrow + 4 * s0);
        float2 u1 = *(const float2*)(yrow + 4 * s0 + 4);
        y[0] = u0.x; y[1] = u0.y; y[2] = u0.z; y[3] = u0.w; y[4] = u1.x; y[5] = u1.y;
        #pragma unroll
        for (int jj = 0; jj < 4; jj++) {
            float y0 = y[jj], y1 = y[jj + 1], y2 = y[jj + 2];
            #pragma unroll
            for (int oo = 0; oo < 4; oo++) {
                accA[oo][jj] += ((const float*)&wA[0])[oo] * y0
                              + ((const float*)&wA[1])[oo] * y1
                              + ((const float*)&wA[2])[oo] * y2;
                accB[oo][jj] += ((const float*)&wB[0])[oo] * y0
                              + ((const float*)&wB[1])[oo] * y1
                              + ((const float*)&wB[2])[oo] * y2;
            }
        }
    }

    // ---- Epilogue: residual + sigmoid(A)*tanh(B), float4 stores ----
    float* ob = out + (size_t)b * (HID * LEN);
    #pragma unroll
    for (int oo = 0; oo < 4; oo++) {
        size_t off = (size_t)(o0 + oo) * LEN + p0 + 4 * s0;
        float4 r = *(const float4*)(hb + off);
        const float* rr = (const float*)&r;
        float4 v;
        float* vp = (float*)&v;
        #pragma unroll
        for (int jj = 0; jj < 4; jj++) {
            float a = accA[oo][jj];
            float c = accB[oo][jj];
            c = fminf(fmaxf(c, -20.0f), 20.0f);
            float sg = 1.0f / (1.0f + __expf(-a));
            float e2 = __expf(-2.0f * c);
            float th = (1.0f - e2) / (1.0f + e2);
            vp[jj] = rr[jj] + sg * th;
        }
        *(float4*)(ob + off) = v;
    }
}

extern "C" void kernel_launch(void* const* d_in, const int* in_sizes, int n_in,
                              void* d_out, int out_size, void* d_ws, size_t ws_size,
                              hipStream_t stream) {
    const float* h    = (const float*)d_in[0];
    const float* kern = (const float*)d_in[1];
    const float* bias = (const float*)d_in[2];
    const float* cw   = (const float*)d_in[3];
    const float* cb   = (const float*)d_in[4];
    float* outp = (float*)d_out;

    const size_t rp_bytes = (size_t)16 * NKL * 6144 * sizeof(float);  // 50.3 MB
    const int use_rp = (d_ws != nullptr && ws_size >= rp_bytes) ? 1 : 0;
    float* rp = (float*)d_ws;

    if (use_rp) repack_kernel<<<2048, 256, 0, stream>>>(kern, rp);
    univnet_fused<<<4096, 256, 0, stream>>>(h, kern, bias, cw, cb, rp, outp, use_rp);
}

// Round 4
// 247.417 us; speedup vs baseline: 1.5938x; 1.3624x over previous
//
#include <hip/hip_runtime.h>

static constexpr int HID = 32;
static constexpr int LEN = 32768;
static constexpr int NKL = 128;
static constexpr int HOP = 256;
#define SLOPE 0.2f

typedef short short8 __attribute__((ext_vector_type(8)));
typedef float floatx4 __attribute__((ext_vector_type(4)));

// LDS map (bytes), one __shared__ char arena:
//   [0, 22400)      xs_t: 280 rows x 40 bf16 (80 B row)   [phase A..conv]
//                   ys_t: rows 0..271, same layout        [conv epi..LVC]
//                   os  : 32 rows x 264 bf16 (528 B row)  [post-LVC]
//   [22400, 28544)  b1: conv weights  [o(32)][k*32+i] bf16 (192 B row)
//   [22400, 34688)  b2: LVC  weights  [o(64)][k*32+i] bf16 (192 B row), after conv
static constexpr int XROW  = 80;     // xs_t/ys_t row bytes (32 ch + 8 pad bf16)
static constexpr int WOFF  = 22400;  // b1/b2 offset
static constexpr int OSROW = 528;    // os row bytes (256 s + 8 pad bf16)
static constexpr int SMEMB = 34688;

__device__ __forceinline__ float leaky(float x) { return x >= 0.0f ? x : SLOPE * x; }

__device__ __forceinline__ unsigned short f2bf(float f) {
    union { float f; unsigned u; } v; v.f = f;
    unsigned r = v.u + 0x7FFFu + ((v.u >> 16) & 1u);   // RNE
    return (unsigned short)(r >> 16);
}
__device__ __forceinline__ float bf2f(unsigned short s) {
    union { unsigned u; float f; } v; v.u = ((unsigned)s) << 16;
    return v.f;
}
__device__ __forceinline__ float gatef(float a, float c) {
    c = fminf(fmaxf(c, -20.0f), 20.0f);
    float sg = 1.0f / (1.0f + __expf(-a));
    float e2 = __expf(-2.0f * c);
    return sg * (1.0f - e2) / (1.0f + e2);
}

__global__ __launch_bounds__(256, 3) void univnet_mfma(
    const float* __restrict__ h,     // [16][32][32768]
    const float* __restrict__ kern,  // [16][32][64][3][128]
    const float* __restrict__ bias,  // [16][64][128]
    const float* __restrict__ cw,    // [32][32][3]
    const float* __restrict__ cb,    // [32]
    float* __restrict__ out)
{
    __shared__ __align__(16) char smem[SMEMB];

    const int blk = blockIdx.x;           // 2048
    const int b   = blk & 15;             // XCD-pinned: blk%8 == b%8
    const int kl  = blk >> 4;
    const int t0  = kl * HOP;
    const int p0  = t0 - 4;               // xs_t col 0 <-> position p0
    const int tid = threadIdx.x;
    const int w   = tid >> 6;
    const int lane = tid & 63;
    const int l15 = lane & 15;
    const int l4  = lane >> 4;

    const float* hb = h + (size_t)b * (HID * LEN);
    const bool edge = (kl == 0) || (kl == NKL - 1);

    // ================= Phase A: stage leaky(h) transposed ==================
    // task tau < 264: i-octet = tau&3, c-quad = tau>>2 (cols c=4cq..4cq+3)
    {
        auto stage = [&](int tau) {
            const int oct = tau & 3, cq = tau >> 2;
            union { unsigned short u[8]; short8 v; } sh[4];
            if (!edge) {
                #pragma unroll
                for (int j = 0; j < 8; ++j) {
                    const int i = oct * 8 + j;
                    float4 f = *(const float4*)(hb + (size_t)i * LEN + p0 + 4 * cq);
                    sh[0].u[j] = f2bf(leaky(f.x));
                    sh[1].u[j] = f2bf(leaky(f.y));
                    sh[2].u[j] = f2bf(leaky(f.z));
                    sh[3].u[j] = f2bf(leaky(f.w));
                }
            } else {
                #pragma unroll
                for (int j = 0; j < 8; ++j) {
                    const int i = oct * 8 + j;
                    #pragma unroll
                    for (int e = 0; e < 4; ++e) {
                        int p = p0 + 4 * cq + e;
                        float v = 0.0f;
                        if (p >= 0 && p < LEN) v = leaky(hb[(size_t)i * LEN + p]);
                        sh[e].u[j] = f2bf(v);
                    }
                }
            }
            #pragma unroll
            for (int e = 0; e < 4; ++e)
                *(short8*)(smem + (4 * cq + e) * XROW + oct * 16) = sh[e].v;
        };
        stage(tid);
        if (tid < 8) stage(256 + tid);
        // zero pad rows 264..279 (bytes [21120, 22400))
        for (int z = tid; z < 320; z += 256)
            ((unsigned*)(smem + 264 * XROW))[z] = 0u;
    }

    // ---- b1: conv weights -> [o][k*32+i] bf16 ----
    #pragma unroll
    for (int j = 0; j < 12; ++j) {
        int e = tid + 256 * j;              // < 3072
        float v = cw[e];
        int o = e / 96; int rem = e - o * 96;
        int i = rem / 3; int kk = rem - i * 3;
        *(unsigned short*)(smem + WOFF + (o * 96 + kk * 32 + i) * 2) = f2bf(v);
    }

    // ---- LVC weight gather into registers (L2-reused across kl siblings) ----
    const int ib2 = tid >> 3, oo8 = tid & 7;
    float kreg[24];
    {
        const float* kbase = kern + (((size_t)b * 32 + ib2) * 64) * 3 * 128 + kl;
        #pragma unroll
        for (int u = 0; u < 8; ++u)
            #pragma unroll
            for (int kk = 0; kk < 3; ++kk)
                kreg[u * 3 + kk] = kbase[(size_t)((oo8 * 8 + u) * 3 + kk) * 128];
    }

    __syncthreads();   // s0: xs_t + b1 ready

    // ================= Conv GEMM: [272 x 96] * [96 x 32] ===================
    // A[c][k*32+i] = xs_t[c+3k][i];  B = b1;  C row = conv out col c_out.
    short8 b1f[2][3];
    #pragma unroll
    for (int tn = 0; tn < 2; ++tn)
        #pragma unroll
        for (int qk = 0; qk < 3; ++qk)
            b1f[tn][qk] = *(const short8*)(smem + WOFF +
                              ((tn * 16 + l15) * 96 + qk * 32 + l4 * 8) * 2);
    const float cbv0 = cb[l15], cbv1 = cb[16 + l15];

    floatx4 cacc[9];
    #pragma unroll
    for (int n = 0; n < 9; ++n) {
        const int tt = w + 4 * n;
        if (tt < 34) {
            const int tm = tt >> 1, tn = tt & 1;
            short8 af[3];
            #pragma unroll
            for (int qk = 0; qk < 3; ++qk)
                af[qk] = *(const short8*)(smem + (tm * 16 + l15 + 3 * qk) * XROW + l4 * 16);
            const float bv = tn ? cbv1 : cbv0;
            floatx4 acc = {bv, bv, bv, bv};
            #pragma unroll
            for (int qk = 0; qk < 3; ++qk)
                acc = __builtin_amdgcn_mfma_f32_16x16x32_bf16(af[qk], b1f[tn][qk], acc, 0, 0, 0);
            cacc[n] = acc;
        }
    }
    __syncthreads();   // s1: all conv reads done; xs_t/b1 now dead

    // ---- conv epilogue: ys_t[c_out][i] = bf16(leaky(acc)), 0 outside signal ----
    #pragma unroll
    for (int n = 0; n < 9; ++n) {
        const int tt = w + 4 * n;
        if (tt < 34) {
            const int tm = tt >> 1, tn = tt & 1;
            const int ich = tn * 16 + l15;
            #pragma unroll
            for (int r = 0; r < 4; ++r) {
                const int c_out = tm * 16 + l4 * 4 + r;
                const int p = t0 - 1 + c_out;
                unsigned short v = ((unsigned)p < (unsigned)LEN) ? f2bf(leaky(cacc[n][r])) : 0;
                *(unsigned short*)(smem + c_out * XROW + ich * 2) = v;
            }
        }
    }
    // ---- drop LVC weights: b2[o][k*32+i] ----
    #pragma unroll
    for (int u = 0; u < 8; ++u)
        #pragma unroll
        for (int kk = 0; kk < 3; ++kk) {
            const int o = oo8 * 8 + u;
            *(unsigned short*)(smem + WOFF + (o * 96 + kk * 32 + ib2) * 2) =
                f2bf(kreg[u * 3 + kk]);
        }
    __syncthreads();   // s2: ys_t + b2 ready

    // ================= LVC GEMM: [256 x 96] * [96 x 64] ====================
    // A[s][k*32+i] = ys_t[s+k][i]. Wave pairs n-tiles (p, p+2) => gate in-reg.
    unsigned garr[2][4][2];
    #pragma unroll
    for (int pp = 0; pp < 2; ++pp) {
        const int oA = pp * 16 + l15, oB = oA + 32;
        short8 b2A[3], b2B[3];
        #pragma unroll
        for (int qk = 0; qk < 3; ++qk) {
            b2A[qk] = *(const short8*)(smem + WOFF + (oA * 96 + qk * 32 + l4 * 8) * 2);
            b2B[qk] = *(const short8*)(smem + WOFF + (oB * 96 + qk * 32 + l4 * 8) * 2);
        }
        const float bA = bias[((size_t)b * 64 + oA) * NKL + kl];
        const float bB = bias[((size_t)b * 64 + oB) * NKL + kl];
        #pragma unroll
        for (int t = 0; t < 4; ++t) {
            const int tm = 4 * t + w;
            short8 af[3];
            #pragma unroll
            for (int qk = 0; qk < 3; ++qk)
                af[qk] = *(const short8*)(smem + (tm * 16 + l15 + qk) * XROW + l4 * 16);
            floatx4 aA = {bA, bA, bA, bA}, aB = {bB, bB, bB, bB};
            #pragma unroll
            for (int qk = 0; qk < 3; ++qk) {
                aA = __builtin_amdgcn_mfma_f32_16x16x32_bf16(af[qk], b2A[qk], aA, 0, 0, 0);
                aB = __builtin_amdgcn_mfma_f32_16x16x32_bf16(af[qk], b2B[qk], aB, 0, 0, 0);
            }
            #pragma unroll
            for (int hp = 0; hp < 2; ++hp) {
                unsigned g0 = f2bf(gatef(aA[2 * hp],     aB[2 * hp]));
                unsigned g1 = f2bf(gatef(aA[2 * hp + 1], aB[2 * hp + 1]));
                garr[pp][t][hp] = g0 | (g1 << 16);
            }
        }
    }
    __syncthreads();   // s3: all LVC reads done; ys_t/b2 dead

    // ---- scatter gates to os[o][s] (bf16) ----
    #pragma unroll
    for (int pp = 0; pp < 2; ++pp) {
        const int o = pp * 16 + l15;
        #pragma unroll
        for (int t = 0; t < 4; ++t) {
            const int sbase = (4 * t + w) * 16 + l4 * 4;
            #pragma unroll
            for (int hp = 0; hp < 2; ++hp)
                *(unsigned*)(smem + o * OSROW + (sbase + 2 * hp) * 2) = garr[pp][t][hp];
        }
    }
    __syncthreads();   // s4

    // ================= Epilogue: out = h + gate, coalesced ================
    {
        const int eo = tid >> 3, e8 = tid & 7;
        const float* hrow = hb + (size_t)eo * LEN + t0;
        float* orow = out + ((size_t)b * HID + eo) * LEN + t0;
        #pragma unroll
        for (int rep = 0; rep < 8; ++rep) {
            const int s = e8 * 4 + 32 * rep;
            uint2 g = *(const uint2*)(smem + eo * OSROW + s * 2);
            float4 hv = *(const float4*)(hrow + s);
            float4 ov;
            ov.x = hv.x + bf2f((unsigned short)(g.x & 0xffff));
            ov.y = hv.y + bf2f((unsigned short)(g.x >> 16));
            ov.z = hv.z + bf2f((unsigned short)(g.y & 0xffff));
            ov.w = hv.w + bf2f((unsigned short)(g.y >> 16));
            *(float4*)(orow + s) = ov;
        }
    }
}

extern "C" void kernel_launch(void* const* d_in, const int* in_sizes, int n_in,
                              void* d_out, int out_size, void* d_ws, size_t ws_size,
                              hipStream_t stream) {
    const float* h    = (const float*)d_in[0];
    const float* kern = (const float*)d_in[1];
    const float* bias = (const float*)d_in[2];
    const float* cw   = (const float*)d_in[3];
    const float* cb   = (const float*)d_in[4];
    float* outp = (float*)d_out;

    univnet_mfma<<<2048, 256, 0, stream>>>(h, kern, bias, cw, cb, outp);
}